// Round 2
// baseline (340.513 us; speedup 1.0000x reference)
//
#include <hip/hip_runtime.h>
#include <hip/hip_bf16.h>

// DiffAttn: B=4, S=4096, EMB=1024, D=128
//   Q = X@Wq+bq (256 cols = Q1|Q2), K likewise, V = X@Wv+bv (128)
//   out = softmax(Q1K1^T/sqrt(D))@V - lam*softmax(Q2K2^T/sqrt(D))@V
// Strategy: bf16 MFMA (16x16x32) with fp32 accumulation everywhere.
// s=1/sqrt(128) folded into stored Q.

typedef __attribute__((ext_vector_type(8))) short bf16x8;   // 8 bf16 = 4 VGPR
typedef __attribute__((ext_vector_type(4))) float f32x4;    // C/D frag

#define MFMA16(a, b, c) __builtin_amdgcn_mfma_f32_16x16x32_bf16((a), (b), (c), 0, 0, 0)
#define LOG2E 1.44269504088896340736f

__device__ __forceinline__ unsigned short f2bf(float x) {
    union { float f; unsigned u; } v; v.f = x;   // RNE float->bf16
    return (unsigned short)((v.u + 0x7FFFu + ((v.u >> 16) & 1u)) >> 16);
}

// ---------------- W transpose + bf16 convert: Wt[640][1024] ----------------
// rows 0-255 = Wq^T, 256-511 = Wk^T, 512-639 = Wv^T
__global__ __launch_bounds__(256) void wtrans_kernel(
    const float* __restrict__ Wq, const float* __restrict__ Wk,
    const float* __restrict__ Wv, unsigned short* __restrict__ Wt) {
    int tid = blockIdx.x * 256 + threadIdx.x;   // 640*1024 total
    int k = tid & 1023, n = tid >> 10;
    float v;
    if (n < 256)      v = Wq[k * 256 + n];
    else if (n < 512) v = Wk[k * 256 + (n - 256)];
    else              v = Wv[k * 128 + (n - 512)];
    Wt[tid] = f2bf(v);
}

// ---------------- QKV projection GEMM ----------------
// grid (128, 5): blockIdx.y = 0,1 -> Q cols 0-127/128-255 (scaled by s)
//                            = 2,3 -> K cols; = 4 -> V
// BM=128, BN=128, BK=32; 4 waves, each 64x64 (acc[4][4] of 16x16)
__global__ __launch_bounds__(256) void proj_kernel(
    const float* __restrict__ X, const unsigned short* __restrict__ Wt,
    const float* __restrict__ bq, const float* __restrict__ bk,
    const float* __restrict__ bv,
    unsigned short* __restrict__ Qs, unsigned short* __restrict__ Kb,
    unsigned short* __restrict__ Vb) {
    __shared__ alignas(16) char lds[16384];   // Xt[128][32]bf16 @0, Wtile[128][32] @8192
    const int nt = blockIdx.y;
    const int m0 = blockIdx.x * 128;
    const int t = threadIdx.x, w = t >> 6, l = t & 63, c = l & 15, g = l >> 4;
    const int wm = w >> 1, wn = w & 1;
    const unsigned short* Wrow = Wt + (long)(nt * 128) * 1024;

    f32x4 acc[4][4];
    const f32x4 fz = {0.f, 0.f, 0.f, 0.f};
#pragma unroll
    for (int i = 0; i < 4; i++)
#pragma unroll
        for (int j = 0; j < 4; j++) acc[i][j] = fz;

    const int srow = t >> 1, sh = t & 1;       // staging: 2 threads/row, 16 elems each
    const int sswz = (srow & 7) << 4;
    for (int k0 = 0; k0 < 1024; k0 += 32) {
        // stage X tile [128][32] fp32 -> bf16 (swizzled)
        const float* xs = X + (long)(m0 + srow) * 1024 + k0 + sh * 16;
        float4 f0 = *(const float4*)(xs + 0);
        float4 f1 = *(const float4*)(xs + 4);
        float4 f2 = *(const float4*)(xs + 8);
        float4 f3 = *(const float4*)(xs + 12);
        // stage W tile [128 n][32 k] bf16 (already transposed+bf16)
        const unsigned short* wsc = Wrow + (long)srow * 1024 + k0 + sh * 16;
        uint4 w0 = *(const uint4*)(wsc + 0);
        uint4 w1 = *(const uint4*)(wsc + 8);
        uint4 xa, xb;
        xa.x = f2bf(f0.x) | ((unsigned)f2bf(f0.y) << 16);
        xa.y = f2bf(f0.z) | ((unsigned)f2bf(f0.w) << 16);
        xa.z = f2bf(f1.x) | ((unsigned)f2bf(f1.y) << 16);
        xa.w = f2bf(f1.z) | ((unsigned)f2bf(f1.w) << 16);
        xb.x = f2bf(f2.x) | ((unsigned)f2bf(f2.y) << 16);
        xb.y = f2bf(f2.z) | ((unsigned)f2bf(f2.w) << 16);
        xb.z = f2bf(f3.x) | ((unsigned)f2bf(f3.y) << 16);
        xb.w = f2bf(f3.z) | ((unsigned)f2bf(f3.w) << 16);
        int base = srow * 64 + sh * 32;
        *(uint4*)(lds + ((base + 0) ^ sswz)) = xa;
        *(uint4*)(lds + ((base + 16) ^ sswz)) = xb;
        *(uint4*)(lds + 8192 + ((base + 0) ^ sswz)) = w0;
        *(uint4*)(lds + 8192 + ((base + 16) ^ sswz)) = w1;
        __syncthreads();

        bf16x8 af[4];
#pragma unroll
        for (int am = 0; am < 4; am++) {
            int r_ = wm * 64 + am * 16 + c;
            af[am] = *(const bf16x8*)(lds + ((r_ * 64 + g * 16) ^ ((c & 7) << 4)));
        }
#pragma unroll
        for (int bn = 0; bn < 4; bn++) {
            int r_ = wn * 64 + bn * 16 + c;
            bf16x8 bfr = *(const bf16x8*)(lds + 8192 + ((r_ * 64 + g * 16) ^ ((c & 7) << 4)));
#pragma unroll
            for (int am = 0; am < 4; am++) acc[am][bn] = MFMA16(af[am], bfr, acc[am][bn]);
        }
        __syncthreads();
    }

    const float* bias; float scale; unsigned short* outp; int ostride, ocol0, boff;
    if (nt < 2)      { bias = bq; boff = nt * 128;       scale = 0.08838834764831845f; outp = Qs; ostride = 256; ocol0 = nt * 128; }
    else if (nt < 4) { bias = bk; boff = (nt - 2) * 128; scale = 1.0f;                 outp = Kb; ostride = 256; ocol0 = (nt - 2) * 128; }
    else             { bias = bv; boff = 0;              scale = 1.0f;                 outp = Vb; ostride = 128; ocol0 = 0; }
#pragma unroll
    for (int bn = 0; bn < 4; bn++) {
        int ncol = wn * 64 + bn * 16 + c;
        float bb = bias[boff + ncol];
#pragma unroll
        for (int am = 0; am < 4; am++) {
#pragma unroll
            for (int r = 0; r < 4; r++) {
                long row = m0 + wm * 64 + am * 16 + 4 * g + r;   // C/D: col=lane&15, row=4*(lane>>4)+r
                outp[row * ostride + ocol0 + ncol] = f2bf((acc[am][bn][r] + bb) * scale);
            }
        }
    }
}

// ---------------- V transpose: Vt[b][128][4096] ----------------
__global__ __launch_bounds__(256) void vtrans_kernel(
    const unsigned short* __restrict__ Vb, unsigned short* __restrict__ Vt) {
    int tid = blockIdx.x * 256 + threadIdx.x;   // 4*128*4096
    int s = tid & 4095, d = (tid >> 12) & 127, b = tid >> 19;
    Vt[tid] = Vb[(((long)b << 12) + s) * 128 + d];
}

// ---------------- flash diff-attention ----------------
// 256 blocks = (b, 64-query block); 4 waves x 16 queries.
// Computes A^T = mfma(Kfrag, Qfrag): col(lane&15)=query -> per-column softmax
// stats via shfl_xor(16/32). out accumulated transposed: out^T = V^T P^T.
#define SOFTMAX_PV_PREP(A0, A1, MREG, SREG, OARR, PDST)                          \
    {                                                                            \
        float mx = fmaxf(fmaxf(fmaxf(A0[0], A0[1]), fmaxf(A0[2], A0[3])),        \
                         fmaxf(fmaxf(A1[0], A1[1]), fmaxf(A1[2], A1[3])));       \
        mx = fmaxf(mx, __shfl_xor(mx, 16));                                      \
        mx = fmaxf(mx, __shfl_xor(mx, 32));                                      \
        float mn = fmaxf(MREG, mx);                                              \
        float al = exp2f((MREG - mn) * LOG2E);                                   \
        float p0 = exp2f((A0[0] - mn) * LOG2E);                                  \
        float p1 = exp2f((A0[1] - mn) * LOG2E);                                  \
        float p2 = exp2f((A0[2] - mn) * LOG2E);                                  \
        float p3 = exp2f((A0[3] - mn) * LOG2E);                                  \
        float p4 = exp2f((A1[0] - mn) * LOG2E);                                  \
        float p5 = exp2f((A1[1] - mn) * LOG2E);                                  \
        float p6 = exp2f((A1[2] - mn) * LOG2E);                                  \
        float p7 = exp2f((A1[3] - mn) * LOG2E);                                  \
        float ps = ((p0 + p1) + (p2 + p3)) + ((p4 + p5) + (p6 + p7));            \
        ps += __shfl_xor(ps, 16);                                                \
        ps += __shfl_xor(ps, 32);                                                \
        SREG = SREG * al + ps;                                                   \
        MREG = mn;                                                               \
        uint2 wa, wb;                                                            \
        wa.x = f2bf(p0) | ((unsigned)f2bf(p1) << 16);                            \
        wa.y = f2bf(p2) | ((unsigned)f2bf(p3) << 16);                            \
        wb.x = f2bf(p4) | ((unsigned)f2bf(p5) << 16);                            \
        wb.y = f2bf(p6) | ((unsigned)f2bf(p7) << 16);                            \
        *(uint2*)((PDST) + ((c * 64 + g * 8) ^ cswz)) = wa;                      \
        *(uint2*)((PDST) + ((c * 64 + 32 + g * 8) ^ cswz)) = wb;                 \
        _Pragma("unroll") for (int dt_ = 0; dt_ < 8; dt_++) (OARR)[dt_] *= al;   \
    }

__global__ __launch_bounds__(256) void attn_kernel(
    const unsigned short* __restrict__ Qs, const unsigned short* __restrict__ Kb,
    const unsigned short* __restrict__ Vt, const float* __restrict__ lam_p,
    float* __restrict__ out) {
    // LDS: K1[32][128] @0 (8K), K2 @8192, Vt-tile[128][32] @16384 (8K),
    //      p-bounce @24576: per-wave 2KB (p1|p2), total 32K
    __shared__ alignas(16) char lds[32768];
    const int t = threadIdx.x, w = t >> 6, l = t & 63, c = l & 15, g = l >> 4;
    const int b = blockIdx.x >> 6, q0 = (blockIdx.x & 63) * 64;
    const long qrow = (long)b * 4096 + q0 + w * 16 + c;
    const unsigned short* Qrow = Qs + qrow * 256;
    bf16x8 q1f[4], q2f[4];   // Q fragments in registers, d-octet = (lane>>4)*8
#pragma unroll
    for (int kc = 0; kc < 4; kc++) {
        q1f[kc] = *(const bf16x8*)(Qrow + kc * 32 + g * 8);
        q2f[kc] = *(const bf16x8*)(Qrow + 128 + kc * 32 + g * 8);
    }
    float m1 = -1e30f, s1 = 0.f, m2 = -1e30f, s2 = 0.f;
    f32x4 o1[8], o2[8];   // out^T accumulators: [d-tile 0..7][4] (128 d x 16 q)
    const f32x4 fz = {0.f, 0.f, 0.f, 0.f};
#pragma unroll
    for (int dt = 0; dt < 8; dt++) { o1[dt] = fz; o2[dt] = fz; }
    char* pb = lds + 24576 + w * 2048;
    const int cswz = (c & 7) << 4;

    for (int kb = 0; kb < 4096; kb += 32) {
        __syncthreads();
        {   // stage K1,K2: 32 rows x 256 bf16; thread: row=t>>3, full 64B segment
            int row = t >> 3, seg = t & 7;
            const unsigned short* src = Kb + ((long)b * 4096 + kb + row) * 256 + seg * 32;
            uint4 u0 = *(const uint4*)(src);
            uint4 u1 = *(const uint4*)(src + 8);
            uint4 u2 = *(const uint4*)(src + 16);
            uint4 u3 = *(const uint4*)(src + 24);
            char* dst = lds + (seg >> 2) * 8192;
            int off = row * 256 + (seg & 3) * 64, rs = (row & 7) << 4;
            *(uint4*)(dst + ((off + 0) ^ rs)) = u0;
            *(uint4*)(dst + ((off + 16) ^ rs)) = u1;
            *(uint4*)(dst + ((off + 32) ^ rs)) = u2;
            *(uint4*)(dst + ((off + 48) ^ rs)) = u3;
        }
        {   // stage Vt tile [128 d][32 keys]
            int row = t >> 1, half = t & 1;
            const unsigned short* src = Vt + (((long)b * 128 + row) << 12) + kb + half * 16;
            uint4 u0 = *(const uint4*)(src);
            uint4 u1 = *(const uint4*)(src + 8);
            int off = row * 64 + half * 32, rs = (row & 7) << 4;
            *(uint4*)(lds + 16384 + ((off + 0) ^ rs)) = u0;
            *(uint4*)(lds + 16384 + ((off + 16) ^ rs)) = u1;
        }
        __syncthreads();

        f32x4 a0, a1;
        // ---- branch 1: A1^T = K1 . Q1^T ----
        a0 = fz; a1 = fz;
#pragma unroll
        for (int kc = 0; kc < 4; kc++) {
            bf16x8 k0f = *(const bf16x8*)(lds + (((c) * 256 + kc * 64 + g * 16) ^ cswz));
            bf16x8 k1f = *(const bf16x8*)(lds + (((16 + c) * 256 + kc * 64 + g * 16) ^ cswz));
            a0 = MFMA16(k0f, q1f[kc], a0);
            a1 = MFMA16(k1f, q1f[kc], a1);
        }
        SOFTMAX_PV_PREP(a0, a1, m1, s1, o1, pb);
        // ---- branch 2: A2^T = K2 . Q2^T ----
        a0 = fz; a1 = fz;
#pragma unroll
        for (int kc = 0; kc < 4; kc++) {
            bf16x8 k0f = *(const bf16x8*)(lds + 8192 + (((c) * 256 + kc * 64 + g * 16) ^ cswz));
            bf16x8 k1f = *(const bf16x8*)(lds + 8192 + (((16 + c) * 256 + kc * 64 + g * 16) ^ cswz));
            a0 = MFMA16(k0f, q2f[kc], a0);
            a1 = MFMA16(k1f, q2f[kc], a1);
        }
        SOFTMAX_PV_PREP(a0, a1, m2, s2, o2, pb + 1024);

        // ---- PV: out^T += Vt-frag x p-frag ----
        bf16x8 pf1 = *(const bf16x8*)(pb + ((c * 64 + g * 16) ^ cswz));
        bf16x8 pf2 = *(const bf16x8*)(pb + 1024 + ((c * 64 + g * 16) ^ cswz));
#pragma unroll
        for (int dt = 0; dt < 8; dt++) {
            int vr = dt * 16 + c;
            bf16x8 vf = *(const bf16x8*)(lds + 16384 + ((vr * 64 + g * 16) ^ cswz));
            o1[dt] = MFMA16(vf, pf1, o1[dt]);
            o2[dt] = MFMA16(vf, pf2, o2[dt]);
        }
    }

    float lam = *lam_p;
    float i1 = 1.f / s1, i2 = lam / s2;
    float* orow = out + qrow * 128;
#pragma unroll
    for (int dt = 0; dt < 8; dt++) {
        float4 v;   // d = dt*16 + 4*g + r
        v.x = o1[dt][0] * i1 - o2[dt][0] * i2;
        v.y = o1[dt][1] * i1 - o2[dt][1] * i2;
        v.z = o1[dt][2] * i1 - o2[dt][2] * i2;
        v.w = o1[dt][3] * i1 - o2[dt][3] * i2;
        *(float4*)(orow + dt * 16 + 4 * g) = v;
    }
}

extern "C" void kernel_launch(void* const* d_in, const int* in_sizes, int n_in,
                              void* d_out, int out_size, void* d_ws, size_t ws_size,
                              hipStream_t stream) {
    const float* X   = (const float*)d_in[0];
    const float* lam = (const float*)d_in[1];
    const float* Wq  = (const float*)d_in[2];
    const float* bq  = (const float*)d_in[3];
    const float* Wk  = (const float*)d_in[4];
    const float* bk  = (const float*)d_in[5];
    const float* Wv  = (const float*)d_in[6];
    const float* bv  = (const float*)d_in[7];
    char* ws = (char*)d_ws;
    // ws layout (25.25 MB): Qs 8M | Kb 8M | Vb 4M | Vt 4M | Wt 1.25M
    unsigned short* Qs = (unsigned short*)(ws);
    unsigned short* Kb = (unsigned short*)(ws + (8u << 20));
    unsigned short* Vb = (unsigned short*)(ws + (16u << 20));
    unsigned short* Vt = (unsigned short*)(ws + (20u << 20));
    unsigned short* Wt = (unsigned short*)(ws + (24u << 20));

    wtrans_kernel<<<2560, 256, 0, stream>>>(Wq, Wk, Wv, Wt);
    proj_kernel<<<dim3(128, 5), 256, 0, stream>>>(X, Wt, bq, bk, bv, Qs, Kb, Vb);
    vtrans_kernel<<<8192, 256, 0, stream>>>(Vb, Vt);
    attn_kernel<<<256, 256, 0, stream>>>(Qs, Kb, Vt, lam, (float*)d_out);
}

// Round 3
// 335.625 us; speedup vs baseline: 1.0146x; 1.0146x over previous
//
#include <hip/hip_runtime.h>
#include <hip/hip_bf16.h>

// DiffAttn: B=4, S=4096, EMB=1024, D=128
//   Q = X@Wq+bq (256 cols = Q1|Q2), K likewise, V = X@Wv+bv (128)
//   out = softmax(Q1K1^T/sqrt(D))@V - lam*softmax(Q2K2^T/sqrt(D))@V
// bf16 MFMA (16x16x32), fp32 accum. Q stored pre-scaled by log2(e)/sqrt(D)
// so softmax runs in exp2 domain with no multiply.
// Flash-decoding key-split (runtime nsplit from ws_size) for occupancy.

typedef __attribute__((ext_vector_type(8))) short bf16x8;   // 8 bf16 = 4 VGPR
typedef __attribute__((ext_vector_type(4))) float f32x4;    // C/D frag

#define MFMA16(a, b, c) __builtin_amdgcn_mfma_f32_16x16x32_bf16((a), (b), (c), 0, 0, 0)

__device__ __forceinline__ unsigned short f2bf(float x) {
    union { float f; unsigned u; } v; v.f = x;   // RNE float->bf16
    return (unsigned short)((v.u + 0x7FFFu + ((v.u >> 16) & 1u)) >> 16);
}
__device__ __forceinline__ unsigned pk2bf(float a, float b) {   // HW v_cvt_pk_bf16_f32
    __hip_bfloat162 h = __float22bfloat162_rn(float2{a, b});
    union { __hip_bfloat162 h2; unsigned u; } cv; cv.h2 = h;
    return cv.u;
}

// ---------------- W transpose + bf16 convert: Wt[640][1024] ----------------
__global__ __launch_bounds__(256) void wtrans_kernel(
    const float* __restrict__ Wq, const float* __restrict__ Wk,
    const float* __restrict__ Wv, unsigned short* __restrict__ Wt) {
    int tid = blockIdx.x * 256 + threadIdx.x;   // 640*1024 total
    int k = tid & 1023, n = tid >> 10;
    float v;
    if (n < 256)      v = Wq[k * 256 + n];
    else if (n < 512) v = Wk[k * 256 + (n - 256)];
    else              v = Wv[k * 128 + (n - 512)];
    Wt[tid] = f2bf(v);
}

// ---------------- QKV projection GEMM ----------------
__global__ __launch_bounds__(256) void proj_kernel(
    const float* __restrict__ X, const unsigned short* __restrict__ Wt,
    const float* __restrict__ bq, const float* __restrict__ bk,
    const float* __restrict__ bv,
    unsigned short* __restrict__ Qs, unsigned short* __restrict__ Kb,
    unsigned short* __restrict__ Vb) {
    __shared__ alignas(16) char lds[16384];   // Xt[128][32]bf16 @0, Wtile @8192
    const int nt = blockIdx.y;
    const int m0 = blockIdx.x * 128;
    const int t = threadIdx.x, w = t >> 6, l = t & 63, c = l & 15, g = l >> 4;
    const int wm = w >> 1, wn = w & 1;
    const unsigned short* Wrow = Wt + (long)(nt * 128) * 1024;

    f32x4 acc[4][4];
    const f32x4 fz = {0.f, 0.f, 0.f, 0.f};
#pragma unroll
    for (int i = 0; i < 4; i++)
#pragma unroll
        for (int j = 0; j < 4; j++) acc[i][j] = fz;

    const int srow = t >> 1, sh = t & 1;
    const int sswz = (srow & 7) << 4;
    for (int k0 = 0; k0 < 1024; k0 += 32) {
        const float* xs = X + (long)(m0 + srow) * 1024 + k0 + sh * 16;
        float4 f0 = *(const float4*)(xs + 0);
        float4 f1 = *(const float4*)(xs + 4);
        float4 f2 = *(const float4*)(xs + 8);
        float4 f3 = *(const float4*)(xs + 12);
        const unsigned short* wsc = Wrow + (long)srow * 1024 + k0 + sh * 16;
        uint4 w0 = *(const uint4*)(wsc + 0);
        uint4 w1 = *(const uint4*)(wsc + 8);
        uint4 xa, xb;
        xa.x = pk2bf(f0.x, f0.y); xa.y = pk2bf(f0.z, f0.w);
        xa.z = pk2bf(f1.x, f1.y); xa.w = pk2bf(f1.z, f1.w);
        xb.x = pk2bf(f2.x, f2.y); xb.y = pk2bf(f2.z, f2.w);
        xb.z = pk2bf(f3.x, f3.y); xb.w = pk2bf(f3.z, f3.w);
        int base = srow * 64 + sh * 32;
        *(uint4*)(lds + ((base + 0) ^ sswz)) = xa;
        *(uint4*)(lds + ((base + 16) ^ sswz)) = xb;
        *(uint4*)(lds + 8192 + ((base + 0) ^ sswz)) = w0;
        *(uint4*)(lds + 8192 + ((base + 16) ^ sswz)) = w1;
        __syncthreads();

        bf16x8 af[4];
#pragma unroll
        for (int am = 0; am < 4; am++) {
            int r_ = wm * 64 + am * 16 + c;
            af[am] = *(const bf16x8*)(lds + ((r_ * 64 + g * 16) ^ ((c & 7) << 4)));
        }
#pragma unroll
        for (int bn = 0; bn < 4; bn++) {
            int r_ = wn * 64 + bn * 16 + c;
            bf16x8 bfr = *(const bf16x8*)(lds + 8192 + ((r_ * 64 + g * 16) ^ ((c & 7) << 4)));
#pragma unroll
            for (int am = 0; am < 4; am++) acc[am][bn] = MFMA16(af[am], bfr, acc[am][bn]);
        }
        __syncthreads();
    }

    // Q scale folds 1/sqrt(128) AND log2(e) so attn softmax is pure exp2.
    const float QSCALE = 0.08838834764831845f * 1.4426950408889634f;
    const float* bias; float scale; unsigned short* outp; int ostride, ocol0, boff;
    if (nt < 2)      { bias = bq; boff = nt * 128;       scale = QSCALE; outp = Qs; ostride = 256; ocol0 = nt * 128; }
    else if (nt < 4) { bias = bk; boff = (nt - 2) * 128; scale = 1.0f;   outp = Kb; ostride = 256; ocol0 = (nt - 2) * 128; }
    else             { bias = bv; boff = 0;              scale = 1.0f;   outp = Vb; ostride = 128; ocol0 = 0; }
#pragma unroll
    for (int bn = 0; bn < 4; bn++) {
        int ncol = wn * 64 + bn * 16 + c;
        float bb = bias[boff + ncol];
#pragma unroll
        for (int am = 0; am < 4; am++) {
#pragma unroll
            for (int r = 0; r < 4; r++) {
                long row = m0 + wm * 64 + am * 16 + 4 * g + r;
                outp[row * ostride + ocol0 + ncol] = f2bf((acc[am][bn][r] + bb) * scale);
            }
        }
    }
}

// ---------------- V transpose: Vt[b][128][4096] ----------------
__global__ __launch_bounds__(256) void vtrans_kernel(
    const unsigned short* __restrict__ Vb, unsigned short* __restrict__ Vt) {
    int tid = blockIdx.x * 256 + threadIdx.x;   // 4*128*4096
    int s = tid & 4095, d = (tid >> 12) & 127, b = tid >> 19;
    Vt[tid] = Vb[(((long)b << 12) + s) * 128 + d];
}

// ---------------- flash diff-attention (key-split) ----------------
// grid (256, nsplit): x = (b, 64-query block), y = key split.
// A^T = mfma(Kfrag, Qfrag); per-query stats via shfl_xor(16/32).
// Defer-max: rescale only when tile max exceeds running max by >8 (log2).
#define SOFTMAX_PV_PREP(A0, A1, MREG, SREG, OARR, PDST)                          \
    {                                                                            \
        float lmx = fmaxf(fmaxf(fmaxf(A0[0], A0[1]), fmaxf(A0[2], A0[3])),       \
                          fmaxf(fmaxf(A1[0], A1[1]), fmaxf(A1[2], A1[3])));      \
        if (__any(lmx > MREG + 8.f)) {                                           \
            float mx = fmaxf(lmx, __shfl_xor(lmx, 16));                          \
            mx = fmaxf(mx, __shfl_xor(mx, 32));                                  \
            float mn = fmaxf(MREG, mx);                                          \
            float al = exp2f(MREG - mn);                                         \
            SREG *= al;                                                          \
            MREG = mn;                                                           \
            _Pragma("unroll") for (int dt_ = 0; dt_ < 8; dt_++) (OARR)[dt_] *= al; \
        }                                                                        \
        float p0 = exp2f(A0[0] - MREG);                                          \
        float p1 = exp2f(A0[1] - MREG);                                          \
        float p2 = exp2f(A0[2] - MREG);                                          \
        float p3 = exp2f(A0[3] - MREG);                                          \
        float p4 = exp2f(A1[0] - MREG);                                          \
        float p5 = exp2f(A1[1] - MREG);                                          \
        float p6 = exp2f(A1[2] - MREG);                                          \
        float p7 = exp2f(A1[3] - MREG);                                          \
        float ps = ((p0 + p1) + (p2 + p3)) + ((p4 + p5) + (p6 + p7));            \
        ps += __shfl_xor(ps, 16);                                                \
        ps += __shfl_xor(ps, 32);                                                \
        SREG += ps;                                                              \
        uint2 wa, wb;                                                            \
        wa.x = pk2bf(p0, p1); wa.y = pk2bf(p2, p3);                              \
        wb.x = pk2bf(p4, p5); wb.y = pk2bf(p6, p7);                              \
        *(uint2*)((PDST) + ((c * 64 + g * 8) ^ cswz)) = wa;                      \
        *(uint2*)((PDST) + ((c * 64 + 32 + g * 8) ^ cswz)) = wb;                 \
    }

__global__ __launch_bounds__(256, 4) void attn_kernel(
    const unsigned short* __restrict__ Qs, const unsigned short* __restrict__ Kb,
    const unsigned short* __restrict__ Vt, const float* __restrict__ lam_p,
    float* __restrict__ out, float* __restrict__ Po, float* __restrict__ Ps,
    int nsplit, int ks) {
    __shared__ alignas(16) char lds[32768];
    const int t = threadIdx.x, w = t >> 6, l = t & 63, c = l & 15, g = l >> 4;
    const int b = blockIdx.x >> 6, q0 = (blockIdx.x & 63) * 64;
    const int split = blockIdx.y;
    const long qrow = (long)b * 4096 + q0 + w * 16 + c;
    const unsigned short* Qrow = Qs + qrow * 256;
    bf16x8 q1f[4], q2f[4];
#pragma unroll
    for (int kc = 0; kc < 4; kc++) {
        q1f[kc] = *(const bf16x8*)(Qrow + kc * 32 + g * 8);
        q2f[kc] = *(const bf16x8*)(Qrow + 128 + kc * 32 + g * 8);
    }
    float m1 = -1e30f, s1 = 0.f, m2 = -1e30f, s2 = 0.f;
    f32x4 o1[8], o2[8];
    const f32x4 fz = {0.f, 0.f, 0.f, 0.f};
#pragma unroll
    for (int dt = 0; dt < 8; dt++) { o1[dt] = fz; o2[dt] = fz; }
    char* pb = lds + 24576 + w * 2048;
    const int cswz = (c & 7) << 4;

    const int kend = split * ks + ks;
    for (int kb = split * ks; kb < kend; kb += 32) {
        __syncthreads();
        {   // stage K1,K2: 32 rows x 256 bf16
            int row = t >> 3, seg = t & 7;
            const unsigned short* src = Kb + ((long)b * 4096 + kb + row) * 256 + seg * 32;
            uint4 u0 = *(const uint4*)(src);
            uint4 u1 = *(const uint4*)(src + 8);
            uint4 u2 = *(const uint4*)(src + 16);
            uint4 u3 = *(const uint4*)(src + 24);
            char* dst = lds + (seg >> 2) * 8192;
            int off = row * 256 + (seg & 3) * 64, rs = (row & 7) << 4;
            *(uint4*)(dst + ((off + 0) ^ rs)) = u0;
            *(uint4*)(dst + ((off + 16) ^ rs)) = u1;
            *(uint4*)(dst + ((off + 32) ^ rs)) = u2;
            *(uint4*)(dst + ((off + 48) ^ rs)) = u3;
        }
        {   // stage Vt tile [128 d][32 keys]
            int row = t >> 1, half = t & 1;
            const unsigned short* src = Vt + (((long)b * 128 + row) << 12) + kb + half * 16;
            uint4 u0 = *(const uint4*)(src);
            uint4 u1 = *(const uint4*)(src + 8);
            int off = row * 64 + half * 32, rs = (row & 7) << 4;
            *(uint4*)(lds + 16384 + ((off + 0) ^ rs)) = u0;
            *(uint4*)(lds + 16384 + ((off + 16) ^ rs)) = u1;
        }
        __syncthreads();

        f32x4 a0, a1;
        a0 = fz; a1 = fz;
#pragma unroll
        for (int kc = 0; kc < 4; kc++) {
            bf16x8 k0f = *(const bf16x8*)(lds + (((c) * 256 + kc * 64 + g * 16) ^ cswz));
            bf16x8 k1f = *(const bf16x8*)(lds + (((16 + c) * 256 + kc * 64 + g * 16) ^ cswz));
            a0 = MFMA16(k0f, q1f[kc], a0);
            a1 = MFMA16(k1f, q1f[kc], a1);
        }
        SOFTMAX_PV_PREP(a0, a1, m1, s1, o1, pb);
        a0 = fz; a1 = fz;
#pragma unroll
        for (int kc = 0; kc < 4; kc++) {
            bf16x8 k0f = *(const bf16x8*)(lds + 8192 + (((c) * 256 + kc * 64 + g * 16) ^ cswz));
            bf16x8 k1f = *(const bf16x8*)(lds + 8192 + (((16 + c) * 256 + kc * 64 + g * 16) ^ cswz));
            a0 = MFMA16(k0f, q2f[kc], a0);
            a1 = MFMA16(k1f, q2f[kc], a1);
        }
        SOFTMAX_PV_PREP(a0, a1, m2, s2, o2, pb + 1024);

        bf16x8 pf1 = *(const bf16x8*)(pb + ((c * 64 + g * 16) ^ cswz));
        bf16x8 pf2 = *(const bf16x8*)(pb + 1024 + ((c * 64 + g * 16) ^ cswz));
#pragma unroll
        for (int dt = 0; dt < 8; dt++) {
            int vr = dt * 16 + c;
            bf16x8 vf = *(const bf16x8*)(lds + 16384 + ((vr * 64 + g * 16) ^ cswz));
            o1[dt] = MFMA16(vf, pf1, o1[dt]);
            o2[dt] = MFMA16(vf, pf2, o2[dt]);
        }
    }

    if (nsplit == 1) {
        float lam = *lam_p;
        float i1 = 1.f / s1, i2 = lam / s2;
        float* orow = out + qrow * 128;
#pragma unroll
        for (int dt = 0; dt < 8; dt++) {
            float4 v;
            v.x = o1[dt][0] * i1 - o2[dt][0] * i2;
            v.y = o1[dt][1] * i1 - o2[dt][1] * i2;
            v.z = o1[dt][2] * i1 - o2[dt][2] * i2;
            v.w = o1[dt][3] * i1 - o2[dt][3] * i2;
            *(float4*)(orow + dt * 16 + 4 * g) = v;
        }
    } else {
        float* po1 = Po + ((qrow * nsplit + split) * 2 + 0) * 128;
        float* po2 = Po + ((qrow * nsplit + split) * 2 + 1) * 128;
#pragma unroll
        for (int dt = 0; dt < 8; dt++) {
            *(f32x4*)(po1 + dt * 16 + 4 * g) = o1[dt];
            *(f32x4*)(po2 + dt * 16 + 4 * g) = o2[dt];
        }
        if (g == 0) {
            float4 st; st.x = m1; st.y = s1; st.z = m2; st.w = s2;
            *(float4*)(Ps + (qrow * nsplit + split) * 4) = st;
        }
    }
}

// ---------------- split combine ----------------
__global__ __launch_bounds__(256) void combine_kernel(
    const float* __restrict__ Po, const float* __restrict__ Ps,
    const float* __restrict__ lam_p, float* __restrict__ out, int nsplit) {
    int tid = blockIdx.x * 256 + threadIdx.x;   // 16384 q * 32 threads
    int q = tid >> 5, dq = (tid & 31) * 4;
    float M1 = -1e30f, M2 = -1e30f;
    for (int s = 0; s < nsplit; s++) {
        float4 st = *(const float4*)(Ps + (long)(q * nsplit + s) * 4);
        M1 = fmaxf(M1, st.x); M2 = fmaxf(M2, st.z);
    }
    float S1 = 0.f, S2 = 0.f;
    float a0 = 0.f, a1 = 0.f, a2 = 0.f, a3 = 0.f;
    float b0 = 0.f, b1 = 0.f, b2 = 0.f, b3 = 0.f;
    for (int s = 0; s < nsplit; s++) {
        float4 st = *(const float4*)(Ps + (long)(q * nsplit + s) * 4);
        float w1 = exp2f(st.x - M1), w2 = exp2f(st.z - M2);
        S1 += st.y * w1; S2 += st.w * w2;
        const float* p1 = Po + (((long)q * nsplit + s) * 2 + 0) * 128 + dq;
        const float* p2 = Po + (((long)q * nsplit + s) * 2 + 1) * 128 + dq;
        float4 v1 = *(const float4*)p1;
        float4 v2 = *(const float4*)p2;
        a0 += v1.x * w1; a1 += v1.y * w1; a2 += v1.z * w1; a3 += v1.w * w1;
        b0 += v2.x * w2; b1 += v2.y * w2; b2 += v2.z * w2; b3 += v2.w * w2;
    }
    float lam = *lam_p;
    float i1 = 1.f / S1, i2 = lam / S2;
    float4 v;
    v.x = a0 * i1 - b0 * i2;
    v.y = a1 * i1 - b1 * i2;
    v.z = a2 * i1 - b2 * i2;
    v.w = a3 * i1 - b3 * i2;
    *(float4*)(out + (long)q * 128 + dq) = v;
}

extern "C" void kernel_launch(void* const* d_in, const int* in_sizes, int n_in,
                              void* d_out, int out_size, void* d_ws, size_t ws_size,
                              hipStream_t stream) {
    const float* X   = (const float*)d_in[0];
    const float* lam = (const float*)d_in[1];
    const float* Wq  = (const float*)d_in[2];
    const float* bq  = (const float*)d_in[3];
    const float* Wk  = (const float*)d_in[4];
    const float* bk  = (const float*)d_in[5];
    const float* Wv  = (const float*)d_in[6];
    const float* bv  = (const float*)d_in[7];
    char* ws = (char*)d_ws;
    // ws: Qs 8M | Kb 8M | Vb 4M | Vt 4M | Wt 1.25M | @26M: Po, Ps
    unsigned short* Qs = (unsigned short*)(ws);
    unsigned short* Kb = (unsigned short*)(ws + (8u << 20));
    unsigned short* Vb = (unsigned short*)(ws + (16u << 20));
    unsigned short* Vt = (unsigned short*)(ws + (20u << 20));
    unsigned short* Wt = (unsigned short*)(ws + (24u << 20));
    const size_t base = (size_t)26 << 20;
    const size_t NQ = 16384;
    int nsplit = 1;
    if (ws_size >= base + NQ * 4 * 2 * 128 * 4 + NQ * 4 * 4 * 4)      nsplit = 4;
    else if (ws_size >= base + NQ * 2 * 2 * 128 * 4 + NQ * 2 * 4 * 4) nsplit = 2;
    float* Po = (float*)(ws + base);
    float* Ps = (float*)(ws + base + NQ * (size_t)nsplit * 2 * 128 * 4);

    wtrans_kernel<<<2560, 256, 0, stream>>>(Wq, Wk, Wv, Wt);
    proj_kernel<<<dim3(128, 5), 256, 0, stream>>>(X, Wt, bq, bk, bv, Qs, Kb, Vb);
    vtrans_kernel<<<8192, 256, 0, stream>>>(Vb, Vt);
    attn_kernel<<<dim3(256, nsplit), 256, 0, stream>>>(Qs, Kb, Vt, lam, (float*)d_out,
                                                       Po, Ps, nsplit, 4096 / nsplit);
    if (nsplit > 1)
        combine_kernel<<<2048, 256, 0, stream>>>(Po, Ps, lam, (float*)d_out, nsplit);
}

// Round 5
// 187.718 us; speedup vs baseline: 1.8140x; 1.7879x over previous
//
#include <hip/hip_runtime.h>
#include <hip/hip_bf16.h>

// DiffAttn: B=4, S=4096, EMB=1024, D=128
//   Q = X@Wq+bq (256 cols = Q1|Q2), K likewise, V = X@Wv+bv (128)
//   out = softmax(Q1K1^T/sqrt(D))@V - lam*softmax(Q2K2^T/sqrt(D))@V
// attn v2.1: 32x32x16 MFMA, swapped QK^T, in-register softmax (cvt_pk +
// permlane32_swap, CORRECTED swap direction: vdst = low-pair word),
// branch-split waves, key-split partials + combine.

typedef __attribute__((ext_vector_type(8))) short bf16x8;    // 8 bf16
typedef __attribute__((ext_vector_type(4))) float f32x4;
typedef __attribute__((ext_vector_type(16))) float f32x16;   // 32x32 C/D

#define MFMA16(a, b, c) __builtin_amdgcn_mfma_f32_16x16x32_bf16((a), (b), (c), 0, 0, 0)
#define MFMA32(a, b, c) __builtin_amdgcn_mfma_f32_32x32x16_bf16((a), (b), (c), 0, 0, 0)

__device__ __forceinline__ unsigned short f2bf(float x) {
    union { float f; unsigned u; } v; v.f = x;   // RNE float->bf16
    return (unsigned short)((v.u + 0x7FFFu + ((v.u >> 16) & 1u)) >> 16);
}
__device__ __forceinline__ unsigned pk2bf(float a, float b) {   // v_cvt_pk_bf16_f32
    __hip_bfloat162 h = __float22bfloat162_rn(float2{a, b});
    union { __hip_bfloat162 h2; unsigned u; } cv; cv.h2 = h;
    return cv.u;
}

// ---------------- W transpose + bf16 convert: Wt[640][1024] ----------------
__global__ __launch_bounds__(256) void wtrans_kernel(
    const float* __restrict__ Wq, const float* __restrict__ Wk,
    const float* __restrict__ Wv, unsigned short* __restrict__ Wt) {
    int tid = blockIdx.x * 256 + threadIdx.x;   // 640*1024 total
    int k = tid & 1023, n = tid >> 10;
    float v;
    if (n < 256)      v = Wq[k * 256 + n];
    else if (n < 512) v = Wk[k * 256 + (n - 256)];
    else              v = Wv[k * 128 + (n - 512)];
    Wt[tid] = f2bf(v);
}

// ---------------- QKV projection GEMM ----------------
__global__ __launch_bounds__(256) void proj_kernel(
    const float* __restrict__ X, const unsigned short* __restrict__ Wt,
    const float* __restrict__ bq, const float* __restrict__ bk,
    const float* __restrict__ bv,
    unsigned short* __restrict__ Qs, unsigned short* __restrict__ Kb,
    unsigned short* __restrict__ Vb) {
    __shared__ alignas(16) char lds[16384];   // Xt[128][32]bf16 @0, Wtile @8192
    const int nt = blockIdx.y;
    const int m0 = blockIdx.x * 128;
    const int t = threadIdx.x, w = t >> 6, l = t & 63, c = l & 15, g = l >> 4;
    const int wm = w >> 1, wn = w & 1;
    const unsigned short* Wrow = Wt + (long)(nt * 128) * 1024;

    f32x4 acc[4][4];
    const f32x4 fz = {0.f, 0.f, 0.f, 0.f};
#pragma unroll
    for (int i = 0; i < 4; i++)
#pragma unroll
        for (int j = 0; j < 4; j++) acc[i][j] = fz;

    const int srow = t >> 1, sh = t & 1;
    const int sswz = (srow & 7) << 4;
    for (int k0 = 0; k0 < 1024; k0 += 32) {
        const float* xs = X + (long)(m0 + srow) * 1024 + k0 + sh * 16;
        float4 f0 = *(const float4*)(xs + 0);
        float4 f1 = *(const float4*)(xs + 4);
        float4 f2 = *(const float4*)(xs + 8);
        float4 f3 = *(const float4*)(xs + 12);
        const unsigned short* wsc = Wrow + (long)srow * 1024 + k0 + sh * 16;
        uint4 w0 = *(const uint4*)(wsc + 0);
        uint4 w1 = *(const uint4*)(wsc + 8);
        uint4 xa, xb;
        xa.x = pk2bf(f0.x, f0.y); xa.y = pk2bf(f0.z, f0.w);
        xa.z = pk2bf(f1.x, f1.y); xa.w = pk2bf(f1.z, f1.w);
        xb.x = pk2bf(f2.x, f2.y); xb.y = pk2bf(f2.z, f2.w);
        xb.z = pk2bf(f3.x, f3.y); xb.w = pk2bf(f3.z, f3.w);
        int base = srow * 64 + sh * 32;
        *(uint4*)(lds + ((base + 0) ^ sswz)) = xa;
        *(uint4*)(lds + ((base + 16) ^ sswz)) = xb;
        *(uint4*)(lds + 8192 + ((base + 0) ^ sswz)) = w0;
        *(uint4*)(lds + 8192 + ((base + 16) ^ sswz)) = w1;
        __syncthreads();

        bf16x8 af[4];
#pragma unroll
        for (int am = 0; am < 4; am++) {
            int r_ = wm * 64 + am * 16 + c;
            af[am] = *(const bf16x8*)(lds + ((r_ * 64 + g * 16) ^ ((c & 7) << 4)));
        }
#pragma unroll
        for (int bn = 0; bn < 4; bn++) {
            int r_ = wn * 64 + bn * 16 + c;
            bf16x8 bfr = *(const bf16x8*)(lds + 8192 + ((r_ * 64 + g * 16) ^ ((c & 7) << 4)));
#pragma unroll
            for (int am = 0; am < 4; am++) acc[am][bn] = MFMA16(af[am], bfr, acc[am][bn]);
        }
        __syncthreads();
    }

    // Q scale folds 1/sqrt(128) AND log2(e) so attn softmax is pure exp2.
    const float QSCALE = 0.08838834764831845f * 1.4426950408889634f;
    const float* bias; float scale; unsigned short* outp; int ostride, ocol0, boff;
    if (nt < 2)      { bias = bq; boff = nt * 128;       scale = QSCALE; outp = Qs; ostride = 256; ocol0 = nt * 128; }
    else if (nt < 4) { bias = bk; boff = (nt - 2) * 128; scale = 1.0f;   outp = Kb; ostride = 256; ocol0 = (nt - 2) * 128; }
    else             { bias = bv; boff = 0;              scale = 1.0f;   outp = Vb; ostride = 128; ocol0 = 0; }
#pragma unroll
    for (int bn = 0; bn < 4; bn++) {
        int ncol = wn * 64 + bn * 16 + c;
        float bb = bias[boff + ncol];
#pragma unroll
        for (int am = 0; am < 4; am++) {
#pragma unroll
            for (int r = 0; r < 4; r++) {
                long row = m0 + wm * 64 + am * 16 + 4 * g + r;
                outp[row * ostride + ocol0 + ncol] = f2bf((acc[am][bn][r] + bb) * scale);
            }
        }
    }
}

// ---------------- V transpose: Vt[b][128][4096] ----------------
__global__ __launch_bounds__(256) void vtrans_kernel(
    const unsigned short* __restrict__ Vb, unsigned short* __restrict__ Vt) {
    int tid = blockIdx.x * 256 + threadIdx.x;   // 4*128*4096
    int s = tid & 4095, d = (tid >> 12) & 127, b = tid >> 19;
    Vt[tid] = Vb[(((long)b << 12) + s) * 128 + d];
}

// ---------------- flash diff-attention v2.1 ----------------
// 512 threads = 8 waves = 4 q-subblocks x 2 branches. 128 queries/block.
// Swapped QK^T: P^T = mfma32(Kfrag, Qfrag) -> lane holds 16 keys of one
// query column; softmax in-register; P->B-frag via cvt_pk+permlane32_swap.
// permlane32_swap(vdst,vsrc): vdst'={vdst.lo,vsrc.lo}, vsrc'={vdst.hi,vsrc.hi}
// so vdst must be the LOW-key pair word.
__global__ __launch_bounds__(512) void attn2_kernel(
    const unsigned short* __restrict__ Qs, const unsigned short* __restrict__ Kb,
    const unsigned short* __restrict__ Vt,
    float* __restrict__ Po, float* __restrict__ Ps, int nsplit, int ks) {
    __shared__ alignas(16) char lds[24576];  // K1 @0, K2 @8192 (bank-rotated), V @16384
    const int t = threadIdx.x;
    const int w = t >> 6, l = t & 63, r31 = l & 31, hi = l >> 5;
    const int wq = w >> 1, br = w & 1;

    const int total = gridDim.x;
    const int lin = (blockIdx.x & 7) * (total >> 3) + (blockIdx.x >> 3);
    const int grp = lin >> 5, qb = lin & 31;
    const int b = grp / nsplit, split = grp % nsplit;

    const long qrow = (long)b * 4096 + qb * 128 + wq * 32 + r31;
    // Q fragments (own branch): B-operand, 8 d-slices
    bf16x8 qf[8];
    const unsigned short* Qp = Qs + qrow * 256 + br * 128 + hi * 8;
#pragma unroll
    for (int ds = 0; ds < 8; ds++) qf[ds] = *(const bf16x8*)(Qp + ds * 16);

    f32x16 o[4];
    const f32x16 oz = {};
#pragma unroll
    for (int dt = 0; dt < 4; dt++) o[dt] = oz;
    float m = -1e30f, s = 0.f;

    // staging: K 32 rows x 16 segs(32B) by t>>4/t&15; V 128 rows x 4 segs(16B)
    const int krow = t >> 4, kseg = t & 15, khalf = kseg >> 3;
    char* kdst = lds + khalf * 8192;
    const int koff = krow * 256 + (kseg & 7) * 32;
    const int kxor = ((krow & 7) << 4) ^ (khalf << 5);
    const int vrow = t >> 2, vq = t & 3;
    const unsigned short* vsrc = Vt + (((long)b * 128 + vrow) << 12);
    const int voff = (vrow * 64 + vq * 16) ^ ((vrow & 7) << 4);
    const long kbb = (long)b * 4096;

    const int kb0 = split * ks, kend = kb0 + ks;
    uint4 kr0, kr1, vr0;
    {
        const unsigned short* kp = Kb + (kbb + kb0 + krow) * 256 + kseg * 16;
        kr0 = *(const uint4*)(kp);
        kr1 = *(const uint4*)(kp + 8);
        vr0 = *(const uint4*)(vsrc + kb0 + vq * 8);
    }

    const int krd_sw = ((r31 & 7) << 4) ^ (br << 5);
    const char* kbase = lds + br * 8192;

    for (int kb = kb0; kb < kend; kb += 32) {
        __syncthreads();
        *(uint4*)(kdst + ((koff + 0) ^ kxor)) = kr0;
        *(uint4*)(kdst + ((koff + 16) ^ kxor)) = kr1;
        *(uint4*)(lds + 16384 + voff) = vr0;
        __syncthreads();
        {   // prefetch next tile (dummy re-read of first tile on last iter)
            int kn = (kb + 32 < kend) ? kb + 32 : kb0;
            const unsigned short* kp = Kb + (kbb + kn + krow) * 256 + kseg * 16;
            kr0 = *(const uint4*)(kp);
            kr1 = *(const uint4*)(kp + 8);
            vr0 = *(const uint4*)(vsrc + kn + vq * 8);
        }

        // ---- QK^T: P^T[key][q] ----
        f32x16 p = oz;
#pragma unroll
        for (int ds = 0; ds < 8; ds++) {
            bf16x8 kf = *(const bf16x8*)(kbase + ((r31 * 256 + ds * 32 + hi * 16) ^ krd_sw));
            p = MFMA32(kf, qf[ds], p);
        }

        // ---- in-register softmax (exp2 domain; defer-max THR=8) ----
        float lmx = p[0];
#pragma unroll
        for (int i = 1; i < 16; i++) lmx = fmaxf(lmx, p[i]);
        lmx = fmaxf(lmx, __shfl_xor(lmx, 32));
        if (__any(lmx > m + 8.f)) {
            float mn = fmaxf(m, lmx);
            float al = exp2f(m - mn);
            s *= al; m = mn;
#pragma unroll
            for (int dt = 0; dt < 4; dt++) o[dt] *= al;
        }
        float pe[16];
#pragma unroll
        for (int i = 0; i < 16; i++) pe[i] = exp2f(p[i] - m);
        float ps_ = 0.f;
#pragma unroll
        for (int i = 0; i < 16; i++) ps_ += pe[i];
        ps_ += __shfl_xor(ps_, 32);
        s += ps_;

        // ---- P -> PV B-fragments (in-register) ----
        // lane reg r holds key k=(r&3)+8*(r>>2)+4*hi (within 32-key tile).
        // B-frag word j needs keys {2j,2j+1} at k = hi*8+j (tile 0-15) etc.
        // swap(lowpair, highpair): lowpair'={lo.lo|hi.lo}=w(2j), highpair'=w(2j)+4keys
        unsigned cA = pk2bf(pe[0], pe[1]), cB = pk2bf(pe[2], pe[3]);
        unsigned cC = pk2bf(pe[4], pe[5]), cD = pk2bf(pe[6], pe[7]);
        asm volatile("v_permlane32_swap_b32 %0, %1" : "+v"(cA), "+v"(cC));
        asm volatile("v_permlane32_swap_b32 %0, %1" : "+v"(cB), "+v"(cD));
        unsigned dA = pk2bf(pe[8], pe[9]), dB = pk2bf(pe[10], pe[11]);
        unsigned dC = pk2bf(pe[12], pe[13]), dD = pk2bf(pe[14], pe[15]);
        asm volatile("v_permlane32_swap_b32 %0, %1" : "+v"(dA), "+v"(dC));
        asm volatile("v_permlane32_swap_b32 %0, %1" : "+v"(dB), "+v"(dD));
        union { uint4 u; bf16x8 v; } pb0, pb1;
        pb0.u = uint4{cA, cB, cC, cD};   // w0..w3 for keys 0-15
        pb1.u = uint4{dA, dB, dC, dD};   // w0..w3 for keys 16-31

        // ---- PV: O^T[d][q] += V^T-frag x PB ----
#pragma unroll
        for (int dt = 0; dt < 4; dt++) {
            int vr = dt * 32 + r31;
            int vsw = (vr & 7) << 4;
            bf16x8 vf0 = *(const bf16x8*)(lds + 16384 + ((vr * 64 + hi * 16) ^ vsw));
            bf16x8 vf1 = *(const bf16x8*)(lds + 16384 + ((vr * 64 + 32 + hi * 16) ^ vsw));
            o[dt] = MFMA32(vf0, pb0.v, o[dt]);
            o[dt] = MFMA32(vf1, pb1.v, o[dt]);
        }
    }

    // ---- epilogue: per-branch partials ----
    float* po = Po + (((qrow)*nsplit + split) * 2 + br) * 128;
#pragma unroll
    for (int dt = 0; dt < 4; dt++) {
#pragma unroll
        for (int rg = 0; rg < 4; rg++) {
            float4 v;   // d = dt*32 + rg*8 + hi*4 + j
            v.x = o[dt][rg * 4 + 0];
            v.y = o[dt][rg * 4 + 1];
            v.z = o[dt][rg * 4 + 2];
            v.w = o[dt][rg * 4 + 3];
            *(float4*)(po + dt * 32 + rg * 8 + hi * 4) = v;
        }
    }
    if (hi == 0)
        *(float2*)(Ps + (qrow * nsplit + split) * 4 + br * 2) = float2{m, s};
}

// ---------------- split combine ----------------
__global__ __launch_bounds__(256) void combine_kernel(
    const float* __restrict__ Po, const float* __restrict__ Ps,
    const float* __restrict__ lam_p, float* __restrict__ out, int nsplit) {
    int tid = blockIdx.x * 256 + threadIdx.x;   // 16384 q * 32 threads
    int q = tid >> 5, dq = (tid & 31) * 4;
    float M1 = -1e30f, M2 = -1e30f;
    for (int s = 0; s < nsplit; s++) {
        float4 st = *(const float4*)(Ps + (long)(q * nsplit + s) * 4);
        M1 = fmaxf(M1, st.x); M2 = fmaxf(M2, st.z);
    }
    float S1 = 0.f, S2 = 0.f;
    float a0 = 0.f, a1 = 0.f, a2 = 0.f, a3 = 0.f;
    float b0 = 0.f, b1 = 0.f, b2 = 0.f, b3 = 0.f;
    for (int s = 0; s < nsplit; s++) {
        float4 st = *(const float4*)(Ps + (long)(q * nsplit + s) * 4);
        float w1 = exp2f(st.x - M1), w2 = exp2f(st.z - M2);
        S1 += st.y * w1; S2 += st.w * w2;
        const float* p1 = Po + (((long)q * nsplit + s) * 2 + 0) * 128 + dq;
        const float* p2 = Po + (((long)q * nsplit + s) * 2 + 1) * 128 + dq;
        float4 v1 = *(const float4*)p1;
        float4 v2 = *(const float4*)p2;
        a0 += v1.x * w1; a1 += v1.y * w1; a2 += v1.z * w1; a3 += v1.w * w1;
        b0 += v2.x * w2; b1 += v2.y * w2; b2 += v2.z * w2; b3 += v2.w * w2;
    }
    float lam = *lam_p;
    float i1 = 1.f / S1, i2 = lam / S2;
    float4 v;
    v.x = a0 * i1 - b0 * i2;
    v.y = a1 * i1 - b1 * i2;
    v.z = a2 * i1 - b2 * i2;
    v.w = a3 * i1 - b3 * i2;
    *(float4*)(out + (long)q * 128 + dq) = v;
}

extern "C" void kernel_launch(void* const* d_in, const int* in_sizes, int n_in,
                              void* d_out, int out_size, void* d_ws, size_t ws_size,
                              hipStream_t stream) {
    const float* X   = (const float*)d_in[0];
    const float* lam = (const float*)d_in[1];
    const float* Wq  = (const float*)d_in[2];
    const float* bq  = (const float*)d_in[3];
    const float* Wk  = (const float*)d_in[4];
    const float* bk  = (const float*)d_in[5];
    const float* Wv  = (const float*)d_in[6];
    const float* bv  = (const float*)d_in[7];
    char* ws = (char*)d_ws;
    // ws: Qs 8M | Kb 8M | Vb 4M | Vt 4M | Wt 1.25M | @26M: Po, Ps
    unsigned short* Qs = (unsigned short*)(ws);
    unsigned short* Kb = (unsigned short*)(ws + (8u << 20));
    unsigned short* Vb = (unsigned short*)(ws + (16u << 20));
    unsigned short* Vt = (unsigned short*)(ws + (20u << 20));
    unsigned short* Wt = (unsigned short*)(ws + (24u << 20));
    const size_t base = (size_t)26 << 20;
    const size_t NQ = 16384;
    int nsplit = 1;
    if (ws_size >= base + NQ * 4 * 2 * 128 * 4 + NQ * 4 * 4 * 4)      nsplit = 4;
    else if (ws_size >= base + NQ * 2 * 2 * 128 * 4 + NQ * 2 * 4 * 4) nsplit = 2;
    float* Po = (float*)(ws + base);
    float* Ps = (float*)(ws + base + NQ * (size_t)nsplit * 2 * 128 * 4);

    wtrans_kernel<<<2560, 256, 0, stream>>>(Wq, Wk, Wv, Wt);
    proj_kernel<<<dim3(128, 5), 256, 0, stream>>>(X, Wt, bq, bk, bv, Qs, Kb, Vb);
    vtrans_kernel<<<8192, 256, 0, stream>>>(Vb, Vt);
    attn2_kernel<<<128 * nsplit, 512, 0, stream>>>(Qs, Kb, Vt, Po, Ps,
                                                   nsplit, 4096 / nsplit);
    combine_kernel<<<2048, 256, 0, stream>>>(Po, Ps, lam, (float*)d_out, nsplit);
}

// Round 6
// 172.591 us; speedup vs baseline: 1.9729x; 1.0876x over previous
//
#include <hip/hip_runtime.h>
#include <hip/hip_bf16.h>

// DiffAttn: B=4, S=4096, EMB=1024, D=128
//   Q = X@Wq+bq (256 cols = Q1|Q2), K likewise, V = X@Wv+bv (128)
//   out = softmax(Q1K1^T/sqrt(D))@V - lam*softmax(Q2K2^T/sqrt(D))@V
// attn v3: 32x32x16 MFMA, swapped QK^T, in-register softmax with RAW
// v_exp_f32 (exp2f was compiling to ~20-instr OCML path = 70% of VALU),
// balanced max/sum trees, split QK accumulator chains, LDS double-buffer
// with single barrier per iteration.

typedef __attribute__((ext_vector_type(8))) short bf16x8;    // 8 bf16
typedef __attribute__((ext_vector_type(4))) float f32x4;
typedef __attribute__((ext_vector_type(16))) float f32x16;   // 32x32 C/D

#define MFMA16(a, b, c) __builtin_amdgcn_mfma_f32_16x16x32_bf16((a), (b), (c), 0, 0, 0)
#define MFMA32(a, b, c) __builtin_amdgcn_mfma_f32_32x32x16_bf16((a), (b), (c), 0, 0, 0)

__device__ __forceinline__ unsigned short f2bf(float x) {
    union { float f; unsigned u; } v; v.f = x;   // RNE float->bf16
    return (unsigned short)((v.u + 0x7FFFu + ((v.u >> 16) & 1u)) >> 16);
}
__device__ __forceinline__ unsigned pk2bf(float a, float b) {   // v_cvt_pk_bf16_f32
    __hip_bfloat162 h = __float22bfloat162_rn(float2{a, b});
    union { __hip_bfloat162 h2; unsigned u; } cv; cv.h2 = h;
    return cv.u;
}
__device__ __forceinline__ float fexp2(float x) {   // raw v_exp_f32: D = 2^S0
    float r; asm("v_exp_f32 %0, %1" : "=v"(r) : "v"(x)); return r;
}

// ---------------- W transpose + bf16 convert: Wt[640][1024] ----------------
__global__ __launch_bounds__(256) void wtrans_kernel(
    const float* __restrict__ Wq, const float* __restrict__ Wk,
    const float* __restrict__ Wv, unsigned short* __restrict__ Wt) {
    int tid = blockIdx.x * 256 + threadIdx.x;   // 640*1024 total
    int k = tid & 1023, n = tid >> 10;
    float v;
    if (n < 256)      v = Wq[k * 256 + n];
    else if (n < 512) v = Wk[k * 256 + (n - 256)];
    else              v = Wv[k * 128 + (n - 512)];
    Wt[tid] = f2bf(v);
}

// ---------------- QKV projection GEMM ----------------
__global__ __launch_bounds__(256) void proj_kernel(
    const float* __restrict__ X, const unsigned short* __restrict__ Wt,
    const float* __restrict__ bq, const float* __restrict__ bk,
    const float* __restrict__ bv,
    unsigned short* __restrict__ Qs, unsigned short* __restrict__ Kb,
    unsigned short* __restrict__ Vb) {
    __shared__ alignas(16) char lds[16384];   // Xt[128][32]bf16 @0, Wtile @8192
    const int nt = blockIdx.y;
    const int m0 = blockIdx.x * 128;
    const int t = threadIdx.x, w = t >> 6, l = t & 63, c = l & 15, g = l >> 4;
    const int wm = w >> 1, wn = w & 1;
    const unsigned short* Wrow = Wt + (long)(nt * 128) * 1024;

    f32x4 acc[4][4];
    const f32x4 fz = {0.f, 0.f, 0.f, 0.f};
#pragma unroll
    for (int i = 0; i < 4; i++)
#pragma unroll
        for (int j = 0; j < 4; j++) acc[i][j] = fz;

    const int srow = t >> 1, sh = t & 1;
    const int sswz = (srow & 7) << 4;
    for (int k0 = 0; k0 < 1024; k0 += 32) {
        const float* xs = X + (long)(m0 + srow) * 1024 + k0 + sh * 16;
        float4 f0 = *(const float4*)(xs + 0);
        float4 f1 = *(const float4*)(xs + 4);
        float4 f2 = *(const float4*)(xs + 8);
        float4 f3 = *(const float4*)(xs + 12);
        const unsigned short* wsc = Wrow + (long)srow * 1024 + k0 + sh * 16;
        uint4 w0 = *(const uint4*)(wsc + 0);
        uint4 w1 = *(const uint4*)(wsc + 8);
        uint4 xa, xb;
        xa.x = pk2bf(f0.x, f0.y); xa.y = pk2bf(f0.z, f0.w);
        xa.z = pk2bf(f1.x, f1.y); xa.w = pk2bf(f1.z, f1.w);
        xb.x = pk2bf(f2.x, f2.y); xb.y = pk2bf(f2.z, f2.w);
        xb.z = pk2bf(f3.x, f3.y); xb.w = pk2bf(f3.z, f3.w);
        int base = srow * 64 + sh * 32;
        *(uint4*)(lds + ((base + 0) ^ sswz)) = xa;
        *(uint4*)(lds + ((base + 16) ^ sswz)) = xb;
        *(uint4*)(lds + 8192 + ((base + 0) ^ sswz)) = w0;
        *(uint4*)(lds + 8192 + ((base + 16) ^ sswz)) = w1;
        __syncthreads();

        bf16x8 af[4];
#pragma unroll
        for (int am = 0; am < 4; am++) {
            int r_ = wm * 64 + am * 16 + c;
            af[am] = *(const bf16x8*)(lds + ((r_ * 64 + g * 16) ^ ((c & 7) << 4)));
        }
#pragma unroll
        for (int bn = 0; bn < 4; bn++) {
            int r_ = wn * 64 + bn * 16 + c;
            bf16x8 bfr = *(const bf16x8*)(lds + 8192 + ((r_ * 64 + g * 16) ^ ((c & 7) << 4)));
#pragma unroll
            for (int am = 0; am < 4; am++) acc[am][bn] = MFMA16(af[am], bfr, acc[am][bn]);
        }
        __syncthreads();
    }

    // Q scale folds 1/sqrt(128) AND log2(e) so attn softmax is pure exp2.
    const float QSCALE = 0.08838834764831845f * 1.4426950408889634f;
    const float* bias; float scale; unsigned short* outp; int ostride, ocol0, boff;
    if (nt < 2)      { bias = bq; boff = nt * 128;       scale = QSCALE; outp = Qs; ostride = 256; ocol0 = nt * 128; }
    else if (nt < 4) { bias = bk; boff = (nt - 2) * 128; scale = 1.0f;   outp = Kb; ostride = 256; ocol0 = (nt - 2) * 128; }
    else             { bias = bv; boff = 0;              scale = 1.0f;   outp = Vb; ostride = 128; ocol0 = 0; }
#pragma unroll
    for (int bn = 0; bn < 4; bn++) {
        int ncol = wn * 64 + bn * 16 + c;
        float bb = bias[boff + ncol];
#pragma unroll
        for (int am = 0; am < 4; am++) {
#pragma unroll
            for (int r = 0; r < 4; r++) {
                long row = m0 + wm * 64 + am * 16 + 4 * g + r;
                outp[row * ostride + ocol0 + ncol] = f2bf((acc[am][bn][r] + bb) * scale);
            }
        }
    }
}

// ---------------- V transpose: Vt[b][128][4096] ----------------
__global__ __launch_bounds__(256) void vtrans_kernel(
    const unsigned short* __restrict__ Vb, unsigned short* __restrict__ Vt) {
    int tid = blockIdx.x * 256 + threadIdx.x;   // 4*128*4096
    int s = tid & 4095, d = (tid >> 12) & 127, b = tid >> 19;
    Vt[tid] = Vb[(((long)b << 12) + s) * 128 + d];
}

// ---------------- flash diff-attention v3 ----------------
// 512 threads = 8 waves = 4 q-subblocks x 2 branches. 128 queries/block.
// Swapped QK^T: P^T = mfma32(Kfrag, Qfrag); softmax fully in-register;
// P->B-frag via cvt_pk + permlane32_swap (vdst = low-pair word).
// LDS double-buffered (2 x 24KB), ONE barrier per iteration:
//   barrier; ds_write buf[i+1]; global-prefetch i+2; compute buf[i].
__global__ __launch_bounds__(512) void attn2_kernel(
    const unsigned short* __restrict__ Qs, const unsigned short* __restrict__ Kb,
    const unsigned short* __restrict__ Vt,
    float* __restrict__ Po, float* __restrict__ Ps, int nsplit, int ks) {
    __shared__ alignas(16) char lds[49152];  // buf{0,1}: K1 @0, K2 @8192, V @16384
    const int t = threadIdx.x;
    const int w = t >> 6, l = t & 63, r31 = l & 31, hi = l >> 5;
    const int wq = w >> 1, br = w & 1;

    const int total = gridDim.x;
    const int lin = (blockIdx.x & 7) * (total >> 3) + (blockIdx.x >> 3);
    const int grp = lin >> 5, qb = lin & 31;
    const int b = grp / nsplit, split = grp % nsplit;

    const long qrow = (long)b * 4096 + qb * 128 + wq * 32 + r31;
    // Q fragments (own branch): B-operand, 8 d-slices
    bf16x8 qf[8];
    const unsigned short* Qp = Qs + qrow * 256 + br * 128 + hi * 8;
#pragma unroll
    for (int ds = 0; ds < 8; ds++) qf[ds] = *(const bf16x8*)(Qp + ds * 16);

    f32x16 o[4];
    const f32x16 oz = {};
#pragma unroll
    for (int dt = 0; dt < 4; dt++) o[dt] = oz;
    float m = -1e30f, s = 0.f;

    // staging: K 32 rows x 16 segs(32B) by t>>4/t&15; V 128 rows x 4 segs(16B)
    const int krow = t >> 4, kseg = t & 15, khalf = kseg >> 3;
    const int kdoff = khalf * 8192 + (((krow * 256 + (kseg & 7) * 32)) ^
                                      (((krow & 7) << 4) ^ (khalf << 5)));
    const int vrow = t >> 2, vq = t & 3;
    const unsigned short* vsrc = Vt + (((long)b * 128 + vrow) << 12);
    const int voff = 16384 + ((vrow * 64 + vq * 16) ^ ((vrow & 7) << 4));
    const long kbb = (long)b * 4096;

    const int kb0 = split * ks, kend = kb0 + ks;
    uint4 kr0, kr1, vr0;
#define LOADTILE(KN)                                                        \
    {                                                                       \
        const unsigned short* kp = Kb + (kbb + (KN) + krow) * 256 + kseg * 16; \
        kr0 = *(const uint4*)(kp);                                          \
        kr1 = *(const uint4*)(kp + 8);                                      \
        vr0 = *(const uint4*)(vsrc + (KN) + vq * 8);                        \
    }
#define WRITETILE(BUF)                                                      \
    {                                                                       \
        char* bb_ = lds + (BUF)*24576;                                      \
        *(uint4*)(bb_ + kdoff) = kr0;                                       \
        *(uint4*)(bb_ + (kdoff ^ 16)) = kr1;                                \
        *(uint4*)(bb_ + voff) = vr0;                                        \
    }

    LOADTILE(kb0);
    WRITETILE(0);
    {
        int kn = (kb0 + 32 < kend) ? kb0 + 32 : kb0;
        LOADTILE(kn);
    }

    const int krd_sw = ((r31 & 7) << 4) ^ (br << 5);
    const int kbofs = br * 8192;
    int cur = 0;

    for (int kb = kb0; kb < kend; kb += 32) {
        __syncthreads();
        if (kb + 32 < kend) {
            WRITETILE(cur ^ 1);
            int kn = (kb + 64 < kend) ? kb + 64 : kb0;
            LOADTILE(kn);
        }
        const char* bufp = lds + cur * 24576;
        const char* kbase = bufp + kbofs;

        // ---- QK^T: P^T[key][q], two independent 4-deep chains ----
        f32x16 pa = oz, pb_ = oz;
#pragma unroll
        for (int ds = 0; ds < 4; ds++) {
            bf16x8 kfa = *(const bf16x8*)(kbase + ((r31 * 256 + ds * 32 + hi * 16) ^ krd_sw));
            bf16x8 kfb = *(const bf16x8*)(kbase + ((r31 * 256 + (ds + 4) * 32 + hi * 16) ^ krd_sw));
            pa = MFMA32(kfa, qf[ds], pa);
            pb_ = MFMA32(kfb, qf[ds + 4], pb_);
        }
        f32x16 p;
#pragma unroll
        for (int i = 0; i < 16; i++) p[i] = pa[i] + pb_[i];

        // ---- in-register softmax (exp2 domain; defer-max THR=8) ----
        float x0 = fmaxf(fmaxf(p[0], p[1]), fmaxf(p[2], p[3]));
        float x1 = fmaxf(fmaxf(p[4], p[5]), fmaxf(p[6], p[7]));
        float x2 = fmaxf(fmaxf(p[8], p[9]), fmaxf(p[10], p[11]));
        float x3 = fmaxf(fmaxf(p[12], p[13]), fmaxf(p[14], p[15]));
        float lmx = fmaxf(fmaxf(x0, x1), fmaxf(x2, x3));
        lmx = fmaxf(lmx, __shfl_xor(lmx, 32));
        if (__any(lmx > m + 8.f)) {
            float mn = fmaxf(m, lmx);
            float al = fexp2(m - mn);
            s *= al; m = mn;
#pragma unroll
            for (int dt = 0; dt < 4; dt++) o[dt] *= al;
        }
        float pe[16];
#pragma unroll
        for (int i = 0; i < 16; i++) pe[i] = fexp2(p[i] - m);
        float s0 = (pe[0] + pe[1]) + (pe[2] + pe[3]);
        float s1 = (pe[4] + pe[5]) + (pe[6] + pe[7]);
        float s2 = (pe[8] + pe[9]) + (pe[10] + pe[11]);
        float s3 = (pe[12] + pe[13]) + (pe[14] + pe[15]);
        float ps_ = (s0 + s1) + (s2 + s3);
        ps_ += __shfl_xor(ps_, 32);
        s += ps_;

        // ---- P -> PV B-fragments (in-register) ----
        // lane reg r holds key k=(r&3)+8*(r>>2)+4*hi (within 32-key tile).
        // swap(lowpair, highpair): lowpair'={lo.lo|hi.lo}, highpair'={lo.hi|hi.hi}
        unsigned cA = pk2bf(pe[0], pe[1]), cB = pk2bf(pe[2], pe[3]);
        unsigned cC = pk2bf(pe[4], pe[5]), cD = pk2bf(pe[6], pe[7]);
        asm volatile("v_permlane32_swap_b32 %0, %1" : "+v"(cA), "+v"(cC));
        asm volatile("v_permlane32_swap_b32 %0, %1" : "+v"(cB), "+v"(cD));
        unsigned dA = pk2bf(pe[8], pe[9]), dB = pk2bf(pe[10], pe[11]);
        unsigned dC = pk2bf(pe[12], pe[13]), dD = pk2bf(pe[14], pe[15]);
        asm volatile("v_permlane32_swap_b32 %0, %1" : "+v"(dA), "+v"(dC));
        asm volatile("v_permlane32_swap_b32 %0, %1" : "+v"(dB), "+v"(dD));
        union { uint4 u; bf16x8 v; } pb0, pb1;
        pb0.u = uint4{cA, cB, cC, cD};   // w0..w3 for keys 0-15
        pb1.u = uint4{dA, dB, dC, dD};   // w0..w3 for keys 16-31

        // ---- PV: O^T[d][q] += V^T-frag x PB ----
#pragma unroll
        for (int dt = 0; dt < 4; dt++) {
            int vr = dt * 32 + r31;
            int vsw = (vr & 7) << 4;
            bf16x8 vf0 = *(const bf16x8*)(bufp + 16384 + ((vr * 64 + hi * 16) ^ vsw));
            bf16x8 vf1 = *(const bf16x8*)(bufp + 16384 + ((vr * 64 + 32 + hi * 16) ^ vsw));
            o[dt] = MFMA32(vf0, pb0.v, o[dt]);
            o[dt] = MFMA32(vf1, pb1.v, o[dt]);
        }
        cur ^= 1;
    }

    // ---- epilogue: per-branch partials ----
    float* po = Po + (((qrow)*nsplit + split) * 2 + br) * 128;
#pragma unroll
    for (int dt = 0; dt < 4; dt++) {
#pragma unroll
        for (int rg = 0; rg < 4; rg++) {
            float4 v;   // d = dt*32 + rg*8 + hi*4 + j
            v.x = o[dt][rg * 4 + 0];
            v.y = o[dt][rg * 4 + 1];
            v.z = o[dt][rg * 4 + 2];
            v.w = o[dt][rg * 4 + 3];
            *(float4*)(po + dt * 32 + rg * 8 + hi * 4) = v;
        }
    }
    if (hi == 0)
        *(float2*)(Ps + (qrow * nsplit + split) * 4 + br * 2) = float2{m, s};
}

// ---------------- split combine ----------------
__global__ __launch_bounds__(256) void combine_kernel(
    const float* __restrict__ Po, const float* __restrict__ Ps,
    const float* __restrict__ lam_p, float* __restrict__ out, int nsplit) {
    int tid = blockIdx.x * 256 + threadIdx.x;   // 16384 q * 32 threads
    int q = tid >> 5, dq = (tid & 31) * 4;
    float M1 = -1e30f, M2 = -1e30f;
    for (int s = 0; s < nsplit; s++) {
        float4 st = *(const float4*)(Ps + (long)(q * nsplit + s) * 4);
        M1 = fmaxf(M1, st.x); M2 = fmaxf(M2, st.z);
    }
    float S1 = 0.f, S2 = 0.f;
    float a0 = 0.f, a1 = 0.f, a2 = 0.f, a3 = 0.f;
    float b0 = 0.f, b1 = 0.f, b2 = 0.f, b3 = 0.f;
    for (int s = 0; s < nsplit; s++) {
        float4 st = *(const float4*)(Ps + (long)(q * nsplit + s) * 4);
        float w1 = fexp2(st.x - M1), w2 = fexp2(st.z - M2);
        S1 += st.y * w1; S2 += st.w * w2;
        const float* p1 = Po + (((long)q * nsplit + s) * 2 + 0) * 128 + dq;
        const float* p2 = Po + (((long)q * nsplit + s) * 2 + 1) * 128 + dq;
        float4 v1 = *(const float4*)p1;
        float4 v2 = *(const float4*)p2;
        a0 += v1.x * w1; a1 += v1.y * w1; a2 += v1.z * w1; a3 += v1.w * w1;
        b0 += v2.x * w2; b1 += v2.y * w2; b2 += v2.z * w2; b3 += v2.w * w2;
    }
    float lam = *lam_p;
    float i1 = 1.f / S1, i2 = lam / S2;
    float4 v;
    v.x = a0 * i1 - b0 * i2;
    v.y = a1 * i1 - b1 * i2;
    v.z = a2 * i1 - b2 * i2;
    v.w = a3 * i1 - b3 * i2;
    *(float4*)(out + (long)q * 128 + dq) = v;
}

extern "C" void kernel_launch(void* const* d_in, const int* in_sizes, int n_in,
                              void* d_out, int out_size, void* d_ws, size_t ws_size,
                              hipStream_t stream) {
    const float* X   = (const float*)d_in[0];
    const float* lam = (const float*)d_in[1];
    const float* Wq  = (const float*)d_in[2];
    const float* bq  = (const float*)d_in[3];
    const float* Wk  = (const float*)d_in[4];
    const float* bk  = (const float*)d_in[5];
    const float* Wv  = (const float*)d_in[6];
    const float* bv  = (const float*)d_in[7];
    char* ws = (char*)d_ws;
    // ws: Qs 8M | Kb 8M | Vb 4M | Vt 4M | Wt 1.25M | @26M: Po, Ps
    unsigned short* Qs = (unsigned short*)(ws);
    unsigned short* Kb = (unsigned short*)(ws + (8u << 20));
    unsigned short* Vb = (unsigned short*)(ws + (16u << 20));
    unsigned short* Vt = (unsigned short*)(ws + (20u << 20));
    unsigned short* Wt = (unsigned short*)(ws + (24u << 20));
    const size_t base = (size_t)26 << 20;
    const size_t NQ = 16384;
    int nsplit = 1;
    if (ws_size >= base + NQ * 4 * 2 * 128 * 4 + NQ * 4 * 4 * 4)      nsplit = 4;
    else if (ws_size >= base + NQ * 2 * 2 * 128 * 4 + NQ * 2 * 4 * 4) nsplit = 2;
    float* Po = (float*)(ws + base);
    float* Ps = (float*)(ws + base + NQ * (size_t)nsplit * 2 * 128 * 4);

    wtrans_kernel<<<2560, 256, 0, stream>>>(Wq, Wk, Wv, Wt);
    proj_kernel<<<dim3(128, 5), 256, 0, stream>>>(X, Wt, bq, bk, bv, Qs, Kb, Vb);
    vtrans_kernel<<<8192, 256, 0, stream>>>(Vb, Vt);
    attn2_kernel<<<128 * nsplit, 512, 0, stream>>>(Qs, Kb, Vt, Po, Ps,
                                                   nsplit, 4096 / nsplit);
    combine_kernel<<<2048, 256, 0, stream>>>(Po, Ps, lam, (float*)d_out, nsplit);
}